// Round 1
// baseline (487.391 us; speedup 1.0000x reference)
//
#include <hip/hip_runtime.h>

typedef unsigned long long u64;

// Workspace layout:
//   [0, 73728)              : packed weight sign words  swg[o][pos][cw]  (9216 u64)
//   [73728, 73728+6422528)  : packed x words pk[n][h][w][cw] as ulonglong2 {sx, m}
#define PK_OFF 73728
#define NO 8  // output channels per thread

// ---------------------------------------------------------------------------
// Kernel 1: decode codebook weights and pack sign bits.
// wave wid -> (o, pos=kh*3+kw, cw); lane -> channel i = cw*64+lane.
// OIHW flat index f = o*2304 + i*9 + pos; code j = f/12, elem t = f%12.
// ---------------------------------------------------------------------------
__global__ __launch_bounds__(256) void pack_w_kernel(const int* __restrict__ enc,
                                                     const float* __restrict__ cb,
                                                     u64* __restrict__ swg) {
    int wid  = blockIdx.x * 4 + (threadIdx.x >> 6);   // 0..9215
    int lane = threadIdx.x & 63;
    int o   = wid / 36;
    int r   = wid - o * 36;
    int pos = r >> 2;
    int cw  = r & 3;
    int i   = (cw << 6) | lane;
    int f   = o * 2304 + i * 9 + pos;
    int j   = f / 12;
    int t   = f - j * 12;
    float val = cb[enc[j] * 12 + t];
    u64 bits = __ballot(val < 0.0f);
    if (lane == 0) swg[wid] = bits;
}

// ---------------------------------------------------------------------------
// Kernel 2: binarize x into sign/mask bit-words across channels.
// block = (n,h); wave cw handles channels [cw*64, cw*64+64); loop over w.
// Lane c streams a contiguous 56-float row; lines stay hot in L1 across w.
// ---------------------------------------------------------------------------
__global__ __launch_bounds__(256) void pack_x_kernel(const float* __restrict__ x,
                                                     ulonglong2* __restrict__ pk) {
    int nh   = blockIdx.x;            // n*56 + h, 0..1791
    int cw   = threadIdx.x >> 6;
    int lane = threadIdx.x & 63;
    int c    = (cw << 6) | lane;
    int n    = nh / 56;
    int h    = nh - n * 56;
    const float* xp = x + ((size_t)n * 256 + c) * 3136 + (size_t)h * 56;
    ulonglong2* pp  = pk + (size_t)nh * 56 * 4 + cw;
    for (int w = 0; w < 56; ++w) {
        float v = xp[w];
        u64 sx = __ballot(v < 0.0f);
        u64 m  = __ballot(v != 0.0f);
        if (lane == 0) pp[(size_t)w * 4] = make_ulonglong2(sx, m);
    }
}

// ---------------------------------------------------------------------------
// Kernel 3: popcount conv. Thread -> one (n,h,w), NO=8 output channels.
// s[o] = wsum - 2*q[o], wsum = sum popc(m) over valid window words,
// q[o] = sum popc((sx ^ sw[o]) & m). Exact integer math (|s| <= 2304).
// Weights for the block's 8 o's staged in LDS (wave-uniform -> broadcast).
// ---------------------------------------------------------------------------
__global__ __launch_bounds__(256) void conv_kernel(const ulonglong2* __restrict__ pk,
                                                   const u64* __restrict__ swg,
                                                   float* __restrict__ y) {
    __shared__ u64 swl[NO * 36];
    int tid = threadIdx.x;
    int o0  = blockIdx.y * NO;
    for (int idx = tid; idx < NO * 36; idx += 256) swl[idx] = swg[o0 * 36 + idx];
    __syncthreads();

    int gs = blockIdx.x * 256 + tid;   // 0..100351 (grid.x = 392, exact)
    int n  = gs / 3136;
    int s  = gs - n * 3136;
    int h  = s / 56;
    int w  = s - h * 56;

    int q[NO];
#pragma unroll
    for (int j = 0; j < NO; ++j) q[j] = 0;
    int wsum = 0;

#pragma unroll
    for (int dh = 0; dh < 3; ++dh) {
        int hh = h + dh - 1;
        if (hh < 0 || hh >= 56) continue;
#pragma unroll
        for (int dw = 0; dw < 3; ++dw) {
            int ww = w + dw - 1;
            if (ww < 0 || ww >= 56) continue;
            const ulonglong2* p = pk + (((size_t)n * 3136 + hh * 56 + ww) << 2);
            int posb = ((dh * 3 + dw) << 2);
#pragma unroll
            for (int cw = 0; cw < 4; ++cw) {
                ulonglong2 v = p[cw];           // v.x = sx, v.y = m
                wsum += __popcll(v.y);
#pragma unroll
                for (int j = 0; j < NO; ++j) {
                    q[j] += __popcll((v.x ^ swl[j * 36 + posb + cw]) & v.y);
                }
            }
        }
    }

    // y[n][o0+j][h][w]; consecutive tid -> consecutive s -> coalesced per j
    float* yp = y + (size_t)n * 802816 + (size_t)o0 * 3136 + s;
#pragma unroll
    for (int j = 0; j < NO; ++j) yp[(size_t)j * 3136] = (float)(wsum - 2 * q[j]);
}

extern "C" void kernel_launch(void* const* d_in, const int* in_sizes, int n_in,
                              void* d_out, int out_size, void* d_ws, size_t ws_size,
                              hipStream_t stream) {
    const float* x  = (const float*)d_in[0];
    // d_in[1] (latent weight) is unused in the forward value (STE).
    const float* cb = (const float*)d_in[2];
    const int* enc  = (const int*)d_in[3];
    float* y        = (float*)d_out;

    u64* swg       = (u64*)d_ws;
    ulonglong2* pk = (ulonglong2*)((char*)d_ws + PK_OFF);

    hipLaunchKernelGGL(pack_w_kernel, dim3(2304), dim3(256), 0, stream, enc, cb, swg);
    hipLaunchKernelGGL(pack_x_kernel, dim3(1792), dim3(256), 0, stream, x, pk);
    hipLaunchKernelGGL(conv_kernel, dim3(392, 32), dim3(256), 0, stream, pk, swg, y);
}